// Round 1
// baseline (1136.247 us; speedup 1.0000x reference)
//
#include <hip/hip_runtime.h>
#include <stdint.h>

// TernBinLayer: out = binarise(x @ W), x in {-1,+1}, W in {-1,0,+1}.
// Bit-trick kernel: pack x signs via ballot, W columns as P/M bitmasks in
// registers, dot product = AND+popcount. Exact integer math, memory-bound.

#define NROWS 524288
#define DDIM  256

__global__ __launch_bounds__(256, 4)
void ternbin_kernel(const float* __restrict__ x, const float* __restrict__ W,
                    float* __restrict__ out) {
    // Per-column masks: word w = (k&3)*2 + (k>>7), bit b = (k>>2)&31 for
    // element k of the column. This matches the ballot packing below
    // (lane l holds elements 4l..4l+3; ballot j covers component j).
    __shared__ uint32_t ldsP[DDIM][8];
    __shared__ uint32_t ldsM[DDIM][8];
    __shared__ int      ldsC[DDIM];

    const int t = threadIdx.x;   // 0..255

    // ---- Phase 1: thread t builds masks for column t (coalesced W reads) ----
    {
        uint32_t P[8] = {0,0,0,0,0,0,0,0};
        uint32_t M[8] = {0,0,0,0,0,0,0,0};
        #pragma unroll 4
        for (int k = 0; k < DDIM; ++k) {
            float v = W[k * DDIM + t];
            int w = ((k & 3) << 1) | (k >> 7);
            uint32_t bit = 1u << ((k >> 2) & 31);
            if (v > 0.5f)       P[w] |= bit;
            else if (v < -0.5f) M[w] |= bit;
        }
        int c = 0;
        #pragma unroll
        for (int w = 0; w < 8; ++w) {
            ldsP[t][w] = P[w];
            ldsM[t][w] = M[w];
            c += __popc(P[w]) - __popc(M[w]);
        }
        ldsC[t] = c;
    }
    __syncthreads();

    // ---- Phase 2: per-lane register copies for its 4 output columns ----
    const int lane = t & 63;
    uint32_t P[4][8], M[4][8];
    int C[4];
    #pragma unroll
    for (int jc = 0; jc < 4; ++jc) {
        const int col = 4 * lane + jc;
        #pragma unroll
        for (int w = 0; w < 8; ++w) {
            P[jc][w] = ldsP[col][w];
            M[jc][w] = ldsM[col][w];
        }
        C[jc] = ldsC[col];
    }
    __syncthreads();

    // ---- Main loop: one row per wave per iteration, grid-stride ----
    const int wave_in_block   = t >> 6;
    const int waves_per_block = blockDim.x >> 6;
    const int global_wave     = blockIdx.x * waves_per_block + wave_in_block;
    const int total_waves     = gridDim.x * waves_per_block;

    for (int row = global_wave; row < NROWS; row += total_waves) {
        // 64 lanes x 16B = exactly one 1KB row: perfectly coalesced.
        const uint4 xv = *reinterpret_cast<const uint4*>(
            x + (size_t)row * DDIM + 4 * lane);
        // sign bit of +-1.0f == value < 0
        const uint64_t b0 = __ballot((int)xv.x < 0);
        const uint64_t b1 = __ballot((int)xv.y < 0);
        const uint64_t b2 = __ballot((int)xv.z < 0);
        const uint64_t b3 = __ballot((int)xv.w < 0);
        uint32_t s[8];
        s[0] = (uint32_t)b0; s[1] = (uint32_t)(b0 >> 32);
        s[2] = (uint32_t)b1; s[3] = (uint32_t)(b1 >> 32);
        s[4] = (uint32_t)b2; s[5] = (uint32_t)(b2 >> 32);
        s[6] = (uint32_t)b3; s[7] = (uint32_t)(b3 >> 32);

        float4 o;
        float* op = &o.x;
        #pragma unroll
        for (int jc = 0; jc < 4; ++jc) {
            int accP = 0, accM = 0;
            #pragma unroll
            for (int w = 0; w < 8; ++w) {
                accP += __popc(s[w] & P[jc][w]);
                accM += __popc(s[w] & M[jc][w]);
            }
            const int diff = C[jc] + 2 * (accM - accP);
            op[jc] = (diff >= 0) ? 1.0f : -1.0f;
        }
        *reinterpret_cast<float4*>(out + (size_t)row * DDIM + 4 * lane) = o;
    }
}

extern "C" void kernel_launch(void* const* d_in, const int* in_sizes, int n_in,
                              void* d_out, int out_size, void* d_ws, size_t ws_size,
                              hipStream_t stream) {
    const float* x = (const float*)d_in[0];
    const float* W = (const float*)d_in[1];
    float* out = (float*)d_out;
    // 2048 blocks x 4 waves = 8192 waves; 64 rows per wave, exact division.
    ternbin_kernel<<<2048, 256, 0, stream>>>(x, W, out);
}

// Round 2
// 1086.601 us; speedup vs baseline: 1.0457x; 1.0457x over previous
//
#include <hip/hip_runtime.h>
#include <stdint.h>

// TernBinLayer: out = binarise(x @ W), x in {-1,+1}, W in {-1,0,+1}.
// Bit kernel: dot = cntA - 2*popc((s ^ M) & A) per column, where
//   A = nonzero mask of W column, M = negative mask, s = sign bits of row.
// Masks live in per-lane VGPRs (4 cols/lane); row sign bits are wave-uniform
// SGPRs from __ballot. launch_bounds(256,3) -> 170 VGPR budget so the ~64
// mask registers provably fit (round-1's (256,4)=128 budget spilled them).

#define NROWS 524288
#define DDIM  256

typedef uint32_t u32;
typedef unsigned long long u64;

__global__ __launch_bounds__(256, 3)
void ternbin_kernel(const float* __restrict__ x, const float* __restrict__ W,
                    float* __restrict__ out) {
    // Bit layout (matches ballot packing): element k of a column/row ->
    // word ((k&3)<<1)|(k>>7), bit (k>>2)&31.
    __shared__ u32 ldsA[DDIM][9];   // pad to 9 words: spreads init-phase banks
    __shared__ u32 ldsM[DDIM][9];
    __shared__ int ldsC[DDIM];

    const int t = threadIdx.x;   // 0..255

    // ---- Phase 1: thread t builds masks for column t (coalesced W reads) ----
    {
        u32 A[8] = {0,0,0,0,0,0,0,0};
        u32 M[8] = {0,0,0,0,0,0,0,0};
        #pragma unroll 8
        for (int k = 0; k < DDIM; ++k) {
            const float v = W[k * DDIM + t];
            const int   w = ((k & 3) << 1) | (k >> 7);
            const u32 bit = 1u << ((k >> 2) & 31);
            if (v != 0.0f) A[w] |= bit;   // nonzero
            if (v <  0.0f) M[w] |= bit;   // negative
        }
        int c = 0;
        #pragma unroll
        for (int w = 0; w < 8; ++w) {
            ldsA[t][w] = A[w];
            ldsM[t][w] = M[w];
            c += __popc(A[w]);
        }
        ldsC[t] = c;
    }
    __syncthreads();

    // ---- Phase 2: per-lane register copies for its 4 output columns ----
    const int lane = t & 63;
    u32 A[4][8], M[4][8];
    int C[4];
    #pragma unroll
    for (int jc = 0; jc < 4; ++jc) {
        const int col = 4 * lane + jc;
        #pragma unroll
        for (int w = 0; w < 8; ++w) {
            A[jc][w] = ldsA[col][w];
            M[jc][w] = ldsM[col][w];
        }
        C[jc] = ldsC[col];
    }
    __syncthreads();

    // ---- Main loop: each wave owns a contiguous 64-row span, 4-row unroll ----
    const int gwave = (int)((blockIdx.x * blockDim.x + (unsigned)t) >> 6);
    const float* xp = x   + (size_t)gwave * 64 * DDIM + 4 * lane;
    float*       op = out + (size_t)gwave * 64 * DDIM + 4 * lane;

    #pragma unroll 1
    for (int it = 0; it < 16; ++it) {
        uint4 xv[4];
        #pragma unroll
        for (int rr = 0; rr < 4; ++rr)
            xv[rr] = *reinterpret_cast<const uint4*>(xp + (size_t)(4 * it + rr) * DDIM);

        #pragma unroll
        for (int rr = 0; rr < 4; ++rr) {
            // sign bit of +-1.0f == value < 0; ballots give wave-uniform SGPRs
            const u64 b0 = __ballot((int)xv[rr].x < 0);
            const u64 b1 = __ballot((int)xv[rr].y < 0);
            const u64 b2 = __ballot((int)xv[rr].z < 0);
            const u64 b3 = __ballot((int)xv[rr].w < 0);
            u32 s[8];
            s[0] = (u32)b0; s[1] = (u32)(b0 >> 32);
            s[2] = (u32)b1; s[3] = (u32)(b1 >> 32);
            s[4] = (u32)b2; s[5] = (u32)(b2 >> 32);
            s[6] = (u32)b3; s[7] = (u32)(b3 >> 32);

            u32 o[4];
            #pragma unroll
            for (int jc = 0; jc < 4; ++jc) {
                int p = 0;
                #pragma unroll
                for (int w = 0; w < 8; ++w)
                    p += __popc((s[w] ^ M[jc][w]) & A[jc][w]);
                const int d = C[jc] - 2 * p;            // exact integer dot
                // d >= 0 -> +1.0f, d < 0 -> -1.0f (binarise(0) = +1)
                o[jc] = 0x3f800000u | ((u32)d & 0x80000000u);
            }
            uint4 ov;
            ov.x = o[0]; ov.y = o[1]; ov.z = o[2]; ov.w = o[3];
            *reinterpret_cast<uint4*>(op + (size_t)(4 * it + rr) * DDIM) = ov;
        }
    }
}

extern "C" void kernel_launch(void* const* d_in, const int* in_sizes, int n_in,
                              void* d_out, int out_size, void* d_ws, size_t ws_size,
                              hipStream_t stream) {
    const float* x = (const float*)d_in[0];
    const float* W = (const float*)d_in[1];
    float* out = (float*)d_out;
    // 2048 blocks x 4 waves = 8192 waves; each wave owns 64 contiguous rows.
    ternbin_kernel<<<2048, 256, 0, stream>>>(x, W, out);
}

// Round 5
// 936.567 us; speedup vs baseline: 1.2132x; 1.1602x over previous
//
#include <hip/hip_runtime.h>
#include <stdint.h>

// TernBinLayer: out = binarise(x @ W), x in {-1,+1}, W in {-1, 0, +1}.
// Structure (round 3, resubmitted — 2x GPU-acquisition timeout, never ran):
// each LANE owns one output column -> only 16 mask VGPRs (A[8],M[8]) per
// lane, immune to the register-demotion that kept rounds 1-2 at
// VGPR_Count=44 with spilled 64-reg mask arrays.
// Row sign bits come from __ballot -> wave-uniform SGPRs (zero VGPR cost).
// The 4 waves of a block read the same 4 rows (different col-blocks);
// redundant reads hit L1/L2. No LDS, no __syncthreads at all.

#define NROWS 524288
#define DDIM  256
#define BLOCKS 2048
#define ROWS_PER_BLOCK (NROWS / BLOCKS)   // 256
#define ITERS (ROWS_PER_BLOCK / 4)        // 64 iterations of 4 rows

typedef uint32_t u32;
typedef unsigned long long u64;

__global__ __launch_bounds__(256, 4)
void ternbin_kernel(const float* __restrict__ x, const float* __restrict__ W,
                    float* __restrict__ out) {
    const int t    = threadIdx.x;     // 0..255
    const int lane = t & 63;
    const int wv   = t >> 6;          // wave id in block = column block
    const int col  = (wv << 6) | lane;

    // ---- Build masks for THIS lane's column: 16 VGPRs total ----
    // Element k -> word ((k&3)<<1)|(k>>7), bit (k>>2)&31  (matches ballot
    // packing below). Reads W[k][col]: 64 consecutive dwords per wave ->
    // coalesced; W is 256KB, L2/L3-resident after first touch.
    u32 A[8] = {0,0,0,0,0,0,0,0};
    u32 M[8] = {0,0,0,0,0,0,0,0};
    #pragma unroll 8
    for (int k = 0; k < DDIM; ++k) {
        const float v = W[k * DDIM + col];
        const int   w = ((k & 3) << 1) | (k >> 7);
        const u32 bit = 1u << ((k >> 2) & 31);
        if (v != 0.0f) A[w] |= bit;   // nonzero mask
        if (v <  0.0f) M[w] |= bit;   // negative mask
    }
    int C = 0;
    #pragma unroll
    for (int w = 0; w < 8; ++w) C += __popc(A[w]);

    // ---- Main loop: 4 rows per iteration ----
    const size_t row0 = (size_t)blockIdx.x * ROWS_PER_BLOCK;
    const float* xp = x   + row0 * DDIM + 4 * lane;  // lane's 16B slice of a row
    float*       op = out + row0 * DDIM + col;       // lane's output column

    #pragma unroll 1
    for (int it = 0; it < ITERS; ++it) {
        const int rbase = it << 2;
        uint4 xv[4];
        #pragma unroll
        for (int rr = 0; rr < 4; ++rr)
            xv[rr] = *reinterpret_cast<const uint4*>(xp + (size_t)(rbase + rr) * DDIM);

        #pragma unroll
        for (int rr = 0; rr < 4; ++rr) {
            // sign bit of +-1.0f == value < 0; ballots -> wave-uniform SGPRs
            const u64 b0 = __ballot((int)xv[rr].x < 0);
            const u64 b1 = __ballot((int)xv[rr].y < 0);
            const u64 b2 = __ballot((int)xv[rr].z < 0);
            const u64 b3 = __ballot((int)xv[rr].w < 0);
            const u32 s0 = (u32)b0, s1 = (u32)(b0 >> 32);
            const u32 s2 = (u32)b1, s3 = (u32)(b1 >> 32);
            const u32 s4 = (u32)b2, s5 = (u32)(b2 >> 32);
            const u32 s6 = (u32)b3, s7 = (u32)(b3 >> 32);

            // dot = C - 2*popc((s ^ M) & A), exact integer
            int p = 0;
            p += __popc((s0 ^ M[0]) & A[0]);
            p += __popc((s1 ^ M[1]) & A[1]);
            p += __popc((s2 ^ M[2]) & A[2]);
            p += __popc((s3 ^ M[3]) & A[3]);
            p += __popc((s4 ^ M[4]) & A[4]);
            p += __popc((s5 ^ M[5]) & A[5]);
            p += __popc((s6 ^ M[6]) & A[6]);
            p += __popc((s7 ^ M[7]) & A[7]);
            const int d = C - 2 * p;
            // d >= 0 -> +1.0f, else -1.0f (binarise(0) = +1)
            const u32 o = 0x3f800000u | ((u32)d & 0x80000000u);
            // write-only stream: nontemporal keeps out from evicting x in L3
            __builtin_nontemporal_store(o,
                reinterpret_cast<u32*>(op + (size_t)(rbase + rr) * DDIM));
        }
    }
}

extern "C" void kernel_launch(void* const* d_in, const int* in_sizes, int n_in,
                              void* d_out, int out_size, void* d_ws, size_t ws_size,
                              hipStream_t stream) {
    const float* x = (const float*)d_in[0];
    const float* W = (const float*)d_in[1];
    float* out = (float*)d_out;
    // 2048 blocks x 4 waves; block b owns rows [b*256, (b+1)*256).
    ternbin_kernel<<<BLOCKS, 256, 0, stream>>>(x, W, out);
}